// Round 3
// baseline (281.809 us; speedup 1.0000x reference)
//
#include <hip/hip_runtime.h>

// ---------------------------------------------------------------------------
// SelfCrossAttention: B=4, T=1024 (self) + 1024 (cross), d=512, H=8, hd=64.
// I/O dtype: float32 (per the reference); internal compute uses bf16 MFMA
// with fp32 accumulation (threshold has a bf16 floor, floor_eps_k=8).
// Pipeline: qkv_kernel (x2 srcs, fp32->bf16) -> attn_kernel (flash, time
// mask, bf16 workspace) -> proj_kernel (bf16 x fp32W -> fp32 out).
// NaN discipline: every __expf argument is select-clamped to <= 0 BEFORE the
// exp so no inf can exist under any compiler transform.
// ---------------------------------------------------------------------------

typedef short     bf16x8 __attribute__((ext_vector_type(8)));   // 8 bf16 = 4 VGPRs
typedef float     f32x4  __attribute__((ext_vector_type(4)));

#define DI __device__ __forceinline__
#define NEG (-1e9f)

DI unsigned short f2b(float f) {            // fp32 -> bf16 bits, RNE
    union { float f; unsigned int u; } x; x.f = f;
    unsigned int r = x.u + 0x7fffu + ((x.u >> 16) & 1u);
    return (unsigned short)(r >> 16);
}
DI float b2f(unsigned short v) {
    union { unsigned int u; float f; } x; x.u = ((unsigned int)v) << 16;
    return x.f;
}

// ---------------------------------------------------------------------------
// QKV projection: X(4096x512 fp32) @ W(512x1536 fp32) + b, internally bf16,
// scattered into bf16 q/k/v[bh][tglob][j] (bh=b*8+h, tglob=t+src*1024).
// 64x64 tile per block, 256 threads.
// ---------------------------------------------------------------------------
__global__ __launch_bounds__(256)
void qkv_kernel(const float* __restrict__ Xs,
                const float* __restrict__ Xc,
                const float* __restrict__ Ws,
                const float* __restrict__ bs,
                const float* __restrict__ Wc,
                const float* __restrict__ bc,
                unsigned short* __restrict__ qb,
                unsigned short* __restrict__ kb,
                unsigned short* __restrict__ vb)
{
    const int src = blockIdx.z;
    const float* X    = src ? Xc : Xs;
    const float* W    = src ? Wc : Ws;
    const float* bias = src ? bc : bs;

    const int m0 = blockIdx.x * 64;
    const int n0 = blockIdx.y * 64;

    __shared__ unsigned short As[64 * 40];   // bf16, stride 40 elems (80B)
    __shared__ unsigned short Bt[64 * 40];   // transposed W tile: Bt[n][k ^ swz(n)]

    const int tid  = threadIdx.x;
    const int lane = tid & 63;
    const int w    = tid >> 6;
    const int quad = lane >> 4, r16 = lane & 15;

    const f32x4 fzero = {0.f, 0.f, 0.f, 0.f};
    f32x4 acc[2][2];
    acc[0][0] = fzero; acc[0][1] = fzero; acc[1][0] = fzero; acc[1][1] = fzero;

    const int a_row = tid >> 2, a_k = (tid & 3) * 8;     // A: 64 rows x 32 k
    const int b_k   = tid >> 3, b_n8 = (tid & 7) * 8;    // B: 32 k x 64 n
    const int mrow  = (w >> 1) * 32, ncol = (w & 1) * 32;

    for (int k0 = 0; k0 < 512; k0 += 32) {
        const float* ap = X + (size_t)(m0 + a_row) * 512 + k0 + a_k;
        f32x4 a0 = *(const f32x4*)(ap);
        f32x4 a1 = *(const f32x4*)(ap + 4);
        const float* bp = W + (size_t)(k0 + b_k) * 1536 + n0 + b_n8;
        f32x4 b0 = *(const f32x4*)(bp);
        f32x4 b1 = *(const f32x4*)(bp + 4);

        bf16x8 av;
#pragma unroll
        for (int jj = 0; jj < 4; ++jj) {
            ((unsigned short*)&av)[jj]     = f2b(a0[jj]);
            ((unsigned short*)&av)[4 + jj] = f2b(a1[jj]);
        }
        *(bf16x8*)(As + a_row * 40 + a_k) = av;
#pragma unroll
        for (int jj = 0; jj < 8; ++jj) {
            int n = b_n8 + jj;
            int c = ((n >> 3) & 3) * 8;                   // XOR swizzle, mult-of-8
            float bvf = (jj < 4) ? b0[jj & 3] : b1[jj & 3];
            Bt[n * 40 + (b_k ^ c)] = f2b(bvf);
        }
        __syncthreads();

        bf16x8 af[2], bfr[2];
#pragma unroll
        for (int ms = 0; ms < 2; ++ms)
            af[ms] = *(const bf16x8*)(As + (mrow + ms * 16 + r16) * 40 + quad * 8);
#pragma unroll
        for (int ns = 0; ns < 2; ++ns) {
            int n = ncol + ns * 16 + r16;
            int c = ((n >> 3) & 3) * 8;
            bfr[ns] = *(const bf16x8*)(Bt + n * 40 + ((quad * 8) ^ c));
        }
#pragma unroll
        for (int ms = 0; ms < 2; ++ms)
#pragma unroll
            for (int ns = 0; ns < 2; ++ns)
                acc[ms][ns] = __builtin_amdgcn_mfma_f32_16x16x32_bf16(
                    af[ms], bfr[ns], acc[ms][ns], 0, 0, 0);
        __syncthreads();
    }

    // epilogue: C row = quad*4+i, col = r16 (verified gfx950 C/D layout)
#pragma unroll
    for (int ms = 0; ms < 2; ++ms)
#pragma unroll
        for (int ns = 0; ns < 2; ++ns) {
            int n = n0 + ncol + ns * 16 + r16;
            float bbv = bias[n];
            int sec = n >> 9;          // 0=q 1=k 2=v
            int col = n & 511;
            int hh = col >> 6, j = col & 63;
            unsigned short* dst = (sec == 0) ? qb : ((sec == 1) ? kb : vb);
#pragma unroll
            for (int i = 0; i < 4; ++i) {
                int m  = m0 + mrow + ms * 16 + quad * 4 + i;
                int bi = m >> 10, tt = m & 1023;
                int tg = tt + (src << 10);
                float v = acc[ms][ns][i] + bbv;
                dst[(((size_t)(bi * 8 + hh) * 2048 + tg) << 6) + j] = f2b(v);
            }
        }
}

// ---------------------------------------------------------------------------
// Flash attention with elementwise time mask (t_q >= t_k).
// Block = 256 thr (4 waves); block covers 64 q-rows of one (b,h); wave = 16 rows.
// q/k/v workspace is bf16 (written by qkv_kernel).
// ---------------------------------------------------------------------------
__global__ __launch_bounds__(256)
void attn_kernel(const unsigned short* __restrict__ qb,
                 const unsigned short* __restrict__ kb,
                 const unsigned short* __restrict__ vb,
                 const int* __restrict__ t_self,
                 const int* __restrict__ t_cross,
                 unsigned short* __restrict__ y)     // (B,2048,512) bf16
{
    const int bh = blockIdx.y;                 // 0..31
    const int b  = bh >> 3, h = bh & 7;
    const int qt = blockIdx.x;                 // 0..31
    const int tid = threadIdx.x;
    const int w = tid >> 6, lane = tid & 63;
    const int quad = lane >> 4, r16 = lane & 15;

    const unsigned short* Q = qb + (size_t)bh * (2048 * 64);
    const unsigned short* K = kb + (size_t)bh * (2048 * 64);
    const unsigned short* V = vb + (size_t)bh * (2048 * 64);
    const int* tsb = t_self  + b * 1024;
    const int* tcb = t_cross + b * 1024;

    __shared__ unsigned short Vt[64 * 72];     // Vt[j][kk ^ swz(j)], stride 72
    __shared__ float Ps[4][16 * 68];           // per-wave P, stride 68

    const int qrow0 = qt * 64 + w * 16;

    bf16x8 qfrag[2];
#pragma unroll
    for (int ks = 0; ks < 2; ++ks)
        qfrag[ks] = *(const bf16x8*)(Q + (size_t)(qrow0 + r16) * 64 + ks * 32 + quad * 8);

    int tq[4];
#pragma unroll
    for (int i = 0; i < 4; ++i) {
        int qg = qrow0 + quad * 4 + i;
        tq[i] = (qg < 1024) ? tsb[qg] : tcb[qg - 1024];
    }

    const f32x4 fzero = {0.f, 0.f, 0.f, 0.f};
    float m_i[4], l_i[4];
    f32x4 o[4];
#pragma unroll
    for (int i = 0; i < 4; ++i) { m_i[i] = NEG; l_i[i] = 0.f; }
#pragma unroll
    for (int nt = 0; nt < 4; ++nt) o[nt] = fzero;

    const int v_j8 = (tid & 7) * 8;
    float* psw = &Ps[w][0];

    for (int kt = 0; kt < 32; ++kt) {
        __syncthreads();                       // prev PV reads done before Vt overwrite
        // stage V tile transposed
#pragma unroll
        for (int half = 0; half < 2; ++half) {
            int kk = (tid >> 3) + half * 32;
            bf16x8 vv = *(const bf16x8*)(V + (size_t)(kt * 64 + kk) * 64 + v_j8);
#pragma unroll
            for (int jj = 0; jj < 8; ++jj) {
                int j = v_j8 + jj;
                int c = ((j >> 3) & 7) * 8;
                Vt[j * 72 + (kk ^ c)] = ((const unsigned short*)&vv)[jj];
            }
        }

        // S = Q K^T (16 q-rows x 64 keys per wave)
        f32x4 sacc[4];
#pragma unroll
        for (int ct = 0; ct < 4; ++ct) sacc[ct] = fzero;
#pragma unroll
        for (int ct = 0; ct < 4; ++ct) {
            const unsigned short* kr = K + (size_t)(kt * 64 + ct * 16 + r16) * 64;
#pragma unroll
            for (int ks = 0; ks < 2; ++ks) {
                bf16x8 kf = *(const bf16x8*)(kr + ks * 32 + quad * 8);
                sacc[ct] = __builtin_amdgcn_mfma_f32_16x16x32_bf16(
                    qfrag[ks], kf, sacc[ct], 0, 0, 0);
            }
        }

        // mask + online softmax (row = quad*4+i, col = r16)
        float sv[4][4];
        bool okv[4][4];
        float smax[4] = {NEG, NEG, NEG, NEG};
#pragma unroll
        for (int ct = 0; ct < 4; ++ct) {
            int kg = kt * 64 + ct * 16 + r16;
            int tk = (kg < 1024) ? tsb[kg] : tcb[kg - 1024];
#pragma unroll
            for (int i = 0; i < 4; ++i) {
                float s = sacc[ct][i] * 0.125f;      // 1/sqrt(64)
                bool ok = (tq[i] >= tk);
                okv[ct][i] = ok;
                sv[ct][i] = s;
                smax[i] = fmaxf(smax[i], ok ? s : NEG);
            }
        }
#pragma unroll
        for (int off = 1; off < 16; off <<= 1)
#pragma unroll
            for (int i = 0; i < 4; ++i)
                smax[i] = fmaxf(smax[i], __shfl_xor(smax[i], off));

        float alpha[4], rsum[4] = {0.f, 0.f, 0.f, 0.f};
#pragma unroll
        for (int i = 0; i < 4; ++i) {
            float mn = fmaxf(m_i[i], smax[i]);
            alpha[i] = __expf(m_i[i] - mn);          // arg <= 0 always
            m_i[i] = mn;
        }
#pragma unroll
        for (int ct = 0; ct < 4; ++ct)
#pragma unroll
            for (int i = 0; i < 4; ++i) {
                // select the ARGUMENT, not the result: arg <= 0 always.
                float arg = okv[ct][i] ? (sv[ct][i] - m_i[i]) : NEG;
                float p = __expf(arg);
                rsum[i] += p;
                psw[(quad * 4 + i) * 68 + ct * 16 + r16] = p;
            }
#pragma unroll
        for (int off = 1; off < 16; off <<= 1)
#pragma unroll
            for (int i = 0; i < 4; ++i)
                rsum[i] += __shfl_xor(rsum[i], off);
#pragma unroll
        for (int i = 0; i < 4; ++i) l_i[i] = l_i[i] * alpha[i] + rsum[i];
#pragma unroll
        for (int nt = 0; nt < 4; ++nt)
#pragma unroll
            for (int i = 0; i < 4; ++i) o[nt][i] *= alpha[i];

        __syncthreads();                       // Vt ready

        // O += P @ V  (P: A-operand rows = r16; V from Vt)
#pragma unroll
        for (int ks2 = 0; ks2 < 2; ++ks2) {
            const int kbase = ks2 * 32 + quad * 8;
            f32x4 p0 = *(const f32x4*)(psw + r16 * 68 + kbase);
            f32x4 p1 = *(const f32x4*)(psw + r16 * 68 + kbase + 4);
            bf16x8 pfrag;
#pragma unroll
            for (int jj = 0; jj < 4; ++jj) {
                ((unsigned short*)&pfrag)[jj]     = f2b(p0[jj]);
                ((unsigned short*)&pfrag)[4 + jj] = f2b(p1[jj]);
            }
#pragma unroll
            for (int nt = 0; nt < 4; ++nt) {
                int n = nt * 16 + r16;
                int c = ((n >> 3) & 7) * 8;
                bf16x8 vf = *(const bf16x8*)(Vt + n * 72 + (kbase ^ c));
                o[nt] = __builtin_amdgcn_mfma_f32_16x16x32_bf16(pfrag, vf, o[nt], 0, 0, 0);
            }
        }
    }

    // finalize: y[b][t][h*64 + n] = O / l  (bf16 workspace)
#pragma unroll
    for (int i = 0; i < 4; ++i) {
        float inv = (l_i[i] > 0.f) ? (1.f / l_i[i]) : 0.f;
        int tg = qrow0 + quad * 4 + i;
        unsigned short* yr = y + ((size_t)(b * 2048 + tg) * 512) + h * 64;
#pragma unroll
        for (int nt = 0; nt < 4; ++nt)
            yr[nt * 16 + r16] = f2b(o[nt][i] * inv);
    }
}

// ---------------------------------------------------------------------------
// Output projection: Y(8192x512 bf16) @ W_proj(512x512 fp32) + b(fp32),
// fp32 output with tuple-split store.
// ---------------------------------------------------------------------------
__global__ __launch_bounds__(256)
void proj_kernel(const unsigned short* __restrict__ X,
                 const float* __restrict__ W,
                 const float* __restrict__ bias,
                 float* __restrict__ out)
{
    const int m0 = blockIdx.x * 64;
    const int n0 = blockIdx.y * 64;

    __shared__ unsigned short As[64 * 40];
    __shared__ unsigned short Bt[64 * 40];

    const int tid  = threadIdx.x;
    const int lane = tid & 63;
    const int w    = tid >> 6;
    const int quad = lane >> 4, r16 = lane & 15;

    const f32x4 fzero = {0.f, 0.f, 0.f, 0.f};
    f32x4 acc[2][2];
    acc[0][0] = fzero; acc[0][1] = fzero; acc[1][0] = fzero; acc[1][1] = fzero;

    const int a_row = tid >> 2, a_k = (tid & 3) * 8;
    const int b_k   = tid >> 3, b_n8 = (tid & 7) * 8;
    const int mrow  = (w >> 1) * 32, ncol = (w & 1) * 32;

    for (int k0 = 0; k0 < 512; k0 += 32) {
        bf16x8 av = *(const bf16x8*)(X + (size_t)(m0 + a_row) * 512 + k0 + a_k);
        const float* bp = W + (size_t)(k0 + b_k) * 512 + n0 + b_n8;
        f32x4 b0 = *(const f32x4*)(bp);
        f32x4 b1 = *(const f32x4*)(bp + 4);
        *(bf16x8*)(As + a_row * 40 + a_k) = av;
#pragma unroll
        for (int jj = 0; jj < 8; ++jj) {
            int n = b_n8 + jj;
            int c = ((n >> 3) & 3) * 8;
            float bvf = (jj < 4) ? b0[jj & 3] : b1[jj & 3];
            Bt[n * 40 + (b_k ^ c)] = f2b(bvf);
        }
        __syncthreads();

        bf16x8 af[2], bfr[2];
#pragma unroll
        for (int ms = 0; ms < 2; ++ms)
            af[ms] = *(const bf16x8*)(As + (mrow + ms * 16 + r16) * 40 + quad * 8);
#pragma unroll
        for (int ns = 0; ns < 2; ++ns) {
            int n = ncol + ns * 16 + r16;
            int c = ((n >> 3) & 3) * 8;
            bfr[ns] = *(const bf16x8*)(Bt + n * 40 + ((quad * 8) ^ c));
        }
#pragma unroll
        for (int ms = 0; ms < 2; ++ms)
#pragma unroll
            for (int ns = 0; ns < 2; ++ns)
                acc[ms][ns] = __builtin_amdgcn_mfma_f32_16x16x32_bf16(
                    af[ms], bfr[ns], acc[ms][ns], 0, 0, 0);
        __syncthreads();
    }

#pragma unroll
    for (int ms = 0; ms < 2; ++ms)
#pragma unroll
        for (int ns = 0; ns < 2; ++ns) {
            int n = n0 + ncol + ns * 16 + r16;
            float bbv = bias[n];
#pragma unroll
            for (int i = 0; i < 4; ++i) {
                int m  = m0 + mrow + ms * 16 + quad * 4 + i;
                int bi = m >> 11, t = m & 2047;
                float v = acc[ms][ns][i] + bbv;
                size_t idx = (t < 1024)
                    ? ((size_t)bi * 1024 + t) * 512 + n
                    : (size_t)2097152 + ((size_t)bi * 1024 + (t - 1024)) * 512 + n;
                out[idx] = v;
            }
        }
}

// ---------------------------------------------------------------------------
extern "C" void kernel_launch(void* const* d_in, const int* in_sizes, int n_in,
                              void* d_out, int out_size, void* d_ws, size_t ws_size,
                              hipStream_t stream)
{
    const float* self_seq  = (const float*)d_in[0];
    const float* cross_seq = (const float*)d_in[1];
    const int*   t_self    = (const int*)d_in[2];
    const int*   t_cross   = (const int*)d_in[3];
    const float* W_self    = (const float*)d_in[4];
    const float* b_self    = (const float*)d_in[5];
    const float* W_cross   = (const float*)d_in[6];
    const float* b_cross   = (const float*)d_in[7];
    const float* W_proj    = (const float*)d_in[8];
    const float* b_proj    = (const float*)d_in[9];
    float* out = (float*)d_out;

    // workspace: q,k,v,y each 4,194,304 bf16 elems (8 MB) -> 32 MB total
    unsigned short* qbuf = (unsigned short*)d_ws;
    unsigned short* kbuf = qbuf + 4194304;
    unsigned short* vbuf = kbuf + 4194304;
    unsigned short* ybuf = vbuf + 4194304;

    qkv_kernel<<<dim3(64, 24, 2), 256, 0, stream>>>(
        self_seq, cross_seq, W_self, b_self, W_cross, b_cross, qbuf, kbuf, vbuf);

    attn_kernel<<<dim3(32, 32), 256, 0, stream>>>(
        qbuf, kbuf, vbuf, t_self, t_cross, ybuf);

    proj_kernel<<<dim3(128, 8), 256, 0, stream>>>(
        ybuf, W_proj, b_proj, out);
}

// Round 4
// 276.922 us; speedup vs baseline: 1.0176x; 1.0176x over previous
//
#include <hip/hip_runtime.h>

// ---------------------------------------------------------------------------
// SelfCrossAttention: B=4, T=1024+1024, d=512, H=8, hd=64. fp32 I/O,
// bf16 MFMA internals.
// Pipeline: prep (X->bf16, W->bf16 transposed, q-scaled) -> qkv (128x128
// tiles) -> vtrans (V -> [bh][j][t]) -> attn (fixed-max flash, barrier-free
// K-loop, direct-global K/V frags) -> proj.
// Scratch: ws = q,k,v(=y),vt (32 MB); d_out slack holds xb/wt until proj.
// ---------------------------------------------------------------------------

typedef short     bf16x8 __attribute__((ext_vector_type(8)));
typedef float     f32x4  __attribute__((ext_vector_type(4)));

#define DI __device__ __forceinline__

DI unsigned short f2b(float f) {            // fp32 -> bf16 bits, RNE-ish
    union { float f; unsigned int u; } x; x.f = f;
    unsigned int r = x.u + 0x7fffu + ((x.u >> 16) & 1u);
    return (unsigned short)(r >> 16);
}
DI unsigned int fbits(float f) { union { float f; unsigned int u; } x; x.f = f; return x.u; }
DI float bitsf(unsigned int u) { union { unsigned int u; float f; } x; x.u = u; return x.f; }

// ---------------------------------------------------------------------------
// prep: [0,2048) blocks: X fp32 -> bf16 flat copy (both sources, 4.2M elems)
//       [2048,2432): W_self/W_cross transpose+convert [512k][1536n] ->
//                    wt[src][1536n][512k] bf16, q-section (n<512) * 0.125
// ---------------------------------------------------------------------------
__global__ __launch_bounds__(256)
void prep_kernel(const float* __restrict__ Xs, const float* __restrict__ Xc,
                 const float* __restrict__ Ws, const float* __restrict__ Wc,
                 unsigned short* __restrict__ xb, unsigned short* __restrict__ wt)
{
    const int bid = blockIdx.x, tid = threadIdx.x;
    if (bid < 2048) {                        // X convert
        int idx = bid * 2048 + tid * 8;
        const float* s = (idx < 2097152) ? (Xs + idx) : (Xc + idx - 2097152);
        f32x4 a0 = *(const f32x4*)s;
        f32x4 a1 = *(const f32x4*)(s + 4);
        bf16x8 v;
#pragma unroll
        for (int j = 0; j < 4; ++j) {
            ((unsigned short*)&v)[j]     = f2b(a0[j]);
            ((unsigned short*)&v)[4 + j] = f2b(a1[j]);
        }
        *(bf16x8*)(xb + idx) = v;
        return;
    }
    // W transpose tile
    __shared__ unsigned short Tt[64 * 72];
    int tj  = bid - 2048;
    int src = tj >= 192;  tj -= src * 192;
    int k0  = (tj / 24) * 64;
    int n0  = (tj % 24) * 64;
    const float* W = src ? Wc : Ws;
    float sc = (n0 < 512) ? 0.125f : 1.0f;
#pragma unroll
    for (int r = 0; r < 4; ++r) {
        int g  = tid + r * 256;
        int kr = g >> 4, nc4 = (g & 15) * 4;
        f32x4 v = *(const f32x4*)(W + (size_t)(k0 + kr) * 1536 + n0 + nc4);
#pragma unroll
        for (int u = 0; u < 4; ++u)
            Tt[(nc4 + u) * 72 + kr] = f2b(v[u] * sc);
    }
    __syncthreads();
#pragma unroll
    for (int r = 0; r < 2; ++r) {
        int c = tid + r * 256;
        int nl = c >> 3, k8 = (c & 7) * 8;
        *(bf16x8*)(wt + (size_t)src * 786432 + (size_t)(n0 + nl) * 512 + k0 + k8) =
            *(const bf16x8*)(Tt + nl * 72 + k8);
    }
}

// ---------------------------------------------------------------------------
// QKV: xb(4096x512 bf16) @ wt^T(1536x512 bf16, q pre-scaled) + bias.
// 128x128 tile, 256 thr (4 waves, 64x64 quadrant each), BK=32.
// Scatter q/k/v into [bh][tglob][j] bf16. q-bias scaled 0.125 at use.
// ---------------------------------------------------------------------------
__global__ __launch_bounds__(256)
void qkv_kernel(const unsigned short* __restrict__ xb,
                const unsigned short* __restrict__ wt,
                const float* __restrict__ bs, const float* __restrict__ bc,
                unsigned short* __restrict__ qb, unsigned short* __restrict__ kb,
                unsigned short* __restrict__ vb)
{
    const int src = blockIdx.z;
    const int m0 = blockIdx.x * 128, n0 = blockIdx.y * 128;
    const float* bias = src ? bc : bs;
    const unsigned short* X = xb + (size_t)src * 2097152;
    const unsigned short* W = wt + (size_t)src * 786432;

    __shared__ unsigned short As[128 * 40];
    __shared__ unsigned short Bs[128 * 40];

    const int tid = threadIdx.x, lane = tid & 63, w = tid >> 6;
    const int quad = lane >> 4, r16 = lane & 15;
    const int mrow = (w >> 1) * 64, ncol = (w & 1) * 64;

    const f32x4 fzero = {0.f, 0.f, 0.f, 0.f};
    f32x4 acc[4][4];
#pragma unroll
    for (int a = 0; a < 4; ++a)
#pragma unroll
        for (int b = 0; b < 4; ++b) acc[a][b] = fzero;

    const int srow = tid >> 2, sk8 = (tid & 3) * 8;      // staging: 2 rounds

    for (int k0 = 0; k0 < 512; k0 += 32) {
#pragma unroll
        for (int r = 0; r < 2; ++r) {
            int row = srow + r * 64;
            bf16x8 av = *(const bf16x8*)(X + (size_t)(m0 + row) * 512 + k0 + sk8);
            bf16x8 bv = *(const bf16x8*)(W + (size_t)(n0 + row) * 512 + k0 + sk8);
            *(bf16x8*)(As + row * 40 + sk8) = av;
            *(bf16x8*)(Bs + row * 40 + (sk8 ^ (((row >> 3) & 3) * 8))) = bv;
        }
        __syncthreads();

        bf16x8 af[4], bfr[4];
#pragma unroll
        for (int ms = 0; ms < 4; ++ms)
            af[ms] = *(const bf16x8*)(As + (mrow + ms * 16 + r16) * 40 + quad * 8);
#pragma unroll
        for (int ns = 0; ns < 4; ++ns) {
            int n = ncol + ns * 16 + r16;
            bfr[ns] = *(const bf16x8*)(Bs + n * 40 + ((quad * 8) ^ (((n >> 3) & 3) * 8)));
        }
#pragma unroll
        for (int ms = 0; ms < 4; ++ms)
#pragma unroll
            for (int ns = 0; ns < 4; ++ns)
                acc[ms][ns] = __builtin_amdgcn_mfma_f32_16x16x32_bf16(
                    af[ms], bfr[ns], acc[ms][ns], 0, 0, 0);
        __syncthreads();
    }

#pragma unroll
    for (int ms = 0; ms < 4; ++ms)
#pragma unroll
        for (int ns = 0; ns < 4; ++ns) {
            int n = n0 + ncol + ns * 16 + r16;
            int sec = n >> 9, col = n & 511;
            int hh = col >> 6, j = col & 63;
            float bb = bias[n] * ((sec == 0) ? 0.125f : 1.0f);
            unsigned short* dst = (sec == 0) ? qb : ((sec == 1) ? kb : vb);
#pragma unroll
            for (int i = 0; i < 4; ++i) {
                int m = m0 + mrow + ms * 16 + quad * 4 + i;
                int bi = m >> 10, tg = (m & 1023) + (src << 10);
                dst[(((size_t)(bi * 8 + hh) * 2048 + tg) << 6) + j] =
                    f2b(acc[ms][ns][i] + bb);
            }
        }
}

// ---------------------------------------------------------------------------
// vtrans: vb[bh][t][j] -> vt[bh][j][t] (64x64 LDS tile transpose)
// ---------------------------------------------------------------------------
__global__ __launch_bounds__(256)
void vtrans_kernel(const unsigned short* __restrict__ vb,
                   unsigned short* __restrict__ vt)
{
    __shared__ unsigned short Ts[64 * 72];
    const int t0 = blockIdx.x * 64, bh = blockIdx.y, tid = threadIdx.x;
#pragma unroll
    for (int r = 0; r < 2; ++r) {
        int c = tid + r * 256;
        int tr = c >> 3, j8 = (c & 7) * 8;
        bf16x8 v = *(const bf16x8*)(vb + ((size_t)(bh * 2048 + t0 + tr) << 6) + j8);
#pragma unroll
        for (int u = 0; u < 8; ++u)
            Ts[(j8 + u) * 72 + tr] = ((const unsigned short*)&v)[u];
    }
    __syncthreads();
#pragma unroll
    for (int r = 0; r < 2; ++r) {
        int c = tid + r * 256;
        int j = c >> 3, t8 = (c & 7) * 8;
        *(bf16x8*)(vt + (size_t)(bh * 64 + j) * 2048 + t0 + t8) =
            *(const bf16x8*)(Ts + j * 72 + t8);
    }
}

// ---------------------------------------------------------------------------
// attn: fixed-max flash attention, time mask (t_q >= t_k), barrier-free.
// Block = 128 thr (2 waves); wave = 32 q-rows; K-loop 32 tiles of 64 keys.
// Q pre-scaled by 1/8 (folded into W). K frags + V frags direct from global
// (V pre-transposed). P through per-wave fp32 LDS, bf16-rounded at write so
// l == sum of stored P exactly.
// ---------------------------------------------------------------------------
__global__ __launch_bounds__(128)
void attn_kernel(const unsigned short* __restrict__ qb,
                 const unsigned short* __restrict__ kb,
                 const unsigned short* __restrict__ vt,
                 const int* __restrict__ t_self, const int* __restrict__ t_cross,
                 unsigned short* __restrict__ y)
{
    const int qt = blockIdx.x, bh = blockIdx.y;
    const int b = bh >> 3, h = bh & 7;
    const int tid = threadIdx.x, w = tid >> 6, lane = tid & 63;
    const int quad = lane >> 4, r16 = lane & 15;

    const unsigned short* Q = qb + (size_t)bh * 131072;
    const unsigned short* K = kb + (size_t)bh * 131072;
    const unsigned short* V = vt + (size_t)bh * 131072;
    const int* tsb = t_self + b * 1024;
    const int* tcb = t_cross + b * 1024;

    __shared__ float Ps[2][32 * 68];
    float* psw = Ps[w];

    const int qrow0 = qt * 64 + w * 32;

    bf16x8 qfrag[2][2];
#pragma unroll
    for (int g = 0; g < 2; ++g)
#pragma unroll
        for (int ks = 0; ks < 2; ++ks)
            qfrag[g][ks] = *(const bf16x8*)(Q + (size_t)(qrow0 + g * 16 + r16) * 64
                                              + ks * 32 + quad * 8);

    const int* tqp = (qt < 16) ? (tsb + qt * 64) : (tcb + (qt - 16) * 64);
    int tq[2][4];
#pragma unroll
    for (int g = 0; g < 2; ++g)
#pragma unroll
        for (int i = 0; i < 4; ++i)
            tq[g][i] = tqp[w * 32 + g * 16 + quad * 4 + i];

    const f32x4 fzero = {0.f, 0.f, 0.f, 0.f};
    f32x4 o[2][4];
    float rsum[2][4];
#pragma unroll
    for (int g = 0; g < 2; ++g)
#pragma unroll
        for (int nt = 0; nt < 4; ++nt) o[g][nt] = fzero;
#pragma unroll
    for (int g = 0; g < 2; ++g)
#pragma unroll
        for (int i = 0; i < 4; ++i) rsum[g][i] = 0.f;

    for (int kt = 0; kt < 32; ++kt) {
        const int* tkp = (kt < 16) ? (tsb + kt * 64) : (tcb + (kt - 16) * 64);
        int tk[4];
#pragma unroll
        for (int ct = 0; ct < 4; ++ct) tk[ct] = tkp[ct * 16 + r16];

        // K fragments (direct global, B-operand layout)
        bf16x8 kf[4][2];
#pragma unroll
        for (int ct = 0; ct < 4; ++ct)
#pragma unroll
            for (int ks = 0; ks < 2; ++ks)
                kf[ct][ks] = *(const bf16x8*)(K + (size_t)(kt * 64 + ct * 16 + r16) * 64
                                                + ks * 32 + quad * 8);

        f32x4 sacc[2][4];
#pragma unroll
        for (int g = 0; g < 2; ++g)
#pragma unroll
            for (int ct = 0; ct < 4; ++ct) {
                f32x4 a = fzero;
                a = __builtin_amdgcn_mfma_f32_16x16x32_bf16(qfrag[g][0], kf[ct][0], a, 0, 0, 0);
                a = __builtin_amdgcn_mfma_f32_16x16x32_bf16(qfrag[g][1], kf[ct][1], a, 0, 0, 0);
                sacc[g][ct] = a;
            }

        // fixed-max softmax: p = exp(s - 12), masked arg -> -1e9 (exp -> 0).
        // Store bf16-rounded fp32 so l is exactly the sum of what PV consumes.
#pragma unroll
        for (int g = 0; g < 2; ++g)
#pragma unroll
            for (int ct = 0; ct < 4; ++ct)
#pragma unroll
                for (int i = 0; i < 4; ++i) {
                    float s = sacc[g][ct][i];
                    float a = (tq[g][i] >= tk[ct]) ? s : -1e9f;
                    a = fminf(a - 12.0f, 80.0f);
                    float p = __expf(a);
                    unsigned int pr = (fbits(p) + 0x8000u) & 0xFFFF0000u;
                    float f = bitsf(pr);
                    rsum[g][i] += f;
                    psw[(g * 16 + quad * 4 + i) * 68 + ct * 16 + r16] = f;
                }

        // P fragments: read per-wave LDS (A-operand layout), pack bf16
        bf16x8 pf[2][2];
#pragma unroll
        for (int g = 0; g < 2; ++g)
#pragma unroll
            for (int ks2 = 0; ks2 < 2; ++ks2) {
                const float* pp = psw + (g * 16 + r16) * 68 + ks2 * 32 + quad * 8;
                f32x4 p0 = *(const f32x4*)pp;
                f32x4 p1 = *(const f32x4*)(pp + 4);
                union { unsigned int d[4]; bf16x8 v; } u;
                u.d[0] = (fbits(p0[0]) >> 16) | (fbits(p0[1]) & 0xFFFF0000u);
                u.d[1] = (fbits(p0[2]) >> 16) | (fbits(p0[3]) & 0xFFFF0000u);
                u.d[2] = (fbits(p1[0]) >> 16) | (fbits(p1[1]) & 0xFFFF0000u);
                u.d[3] = (fbits(p1[2]) >> 16) | (fbits(p1[3]) & 0xFFFF0000u);
                pf[g][ks2] = u.v;
            }

        // O += P @ V  (V fragments direct from transposed global)
#pragma unroll
        for (int ks2 = 0; ks2 < 2; ++ks2)
#pragma unroll
            for (int nt = 0; nt < 4; ++nt) {
                bf16x8 vf = *(const bf16x8*)(V + (size_t)(nt * 16 + r16) * 2048
                                               + kt * 64 + ks2 * 32 + quad * 8);
                o[0][nt] = __builtin_amdgcn_mfma_f32_16x16x32_bf16(pf[0][ks2], vf, o[0][nt], 0, 0, 0);
                o[1][nt] = __builtin_amdgcn_mfma_f32_16x16x32_bf16(pf[1][ks2], vf, o[1][nt], 0, 0, 0);
            }
    }

    // l reduction across the 16 lanes of each quad-group, then O/l
#pragma unroll
    for (int g = 0; g < 2; ++g)
#pragma unroll
        for (int i = 0; i < 4; ++i) {
#pragma unroll
            for (int off = 1; off < 16; off <<= 1)
                rsum[g][i] += __shfl_xor(rsum[g][i], off);
        }
#pragma unroll
    for (int g = 0; g < 2; ++g)
#pragma unroll
        for (int i = 0; i < 4; ++i) {
            float l = rsum[g][i];
            float inv = (l > 0.f) ? (1.f / l) : 0.f;
            int tg = qrow0 + g * 16 + quad * 4 + i;
            unsigned short* yr = y + ((size_t)(b * 2048 + tg) * 512) + h * 64;
#pragma unroll
            for (int nt = 0; nt < 4; ++nt)
                yr[nt * 16 + r16] = f2b(o[g][nt][i] * inv);
        }
}

// ---------------------------------------------------------------------------
// proj: Y(8192x512 bf16) @ W_proj(512x512 fp32) + b -> fp32 out (tuple split)
// ---------------------------------------------------------------------------
__global__ __launch_bounds__(256)
void proj_kernel(const unsigned short* __restrict__ X,
                 const float* __restrict__ W, const float* __restrict__ bias,
                 float* __restrict__ out)
{
    const int m0 = blockIdx.x * 64, n0 = blockIdx.y * 64;
    __shared__ unsigned short As[64 * 40];
    __shared__ unsigned short Bt[64 * 40];

    const int tid = threadIdx.x, lane = tid & 63, w = tid >> 6;
    const int quad = lane >> 4, r16 = lane & 15;
    const int mrow = (w >> 1) * 32, ncol = (w & 1) * 32;

    const f32x4 fzero = {0.f, 0.f, 0.f, 0.f};
    f32x4 acc[2][2];
    acc[0][0] = fzero; acc[0][1] = fzero; acc[1][0] = fzero; acc[1][1] = fzero;

    const int a_row = tid >> 2, a_k = (tid & 3) * 8;
    const int b_k = tid >> 3, b_n8 = (tid & 7) * 8;

    for (int k0 = 0; k0 < 512; k0 += 32) {
        bf16x8 av = *(const bf16x8*)(X + (size_t)(m0 + a_row) * 512 + k0 + a_k);
        const float* bp = W + (size_t)(k0 + b_k) * 512 + n0 + b_n8;
        f32x4 b0 = *(const f32x4*)bp;
        f32x4 b1 = *(const f32x4*)(bp + 4);
        *(bf16x8*)(As + a_row * 40 + a_k) = av;
#pragma unroll
        for (int jj = 0; jj < 8; ++jj) {
            int n = b_n8 + jj;
            int c = ((n >> 3) & 3) * 8;
            Bt[n * 40 + (b_k ^ c)] = f2b((jj < 4) ? b0[jj & 3] : b1[jj & 3]);
        }
        __syncthreads();

        bf16x8 af[2], bfr[2];
#pragma unroll
        for (int ms = 0; ms < 2; ++ms)
            af[ms] = *(const bf16x8*)(As + (mrow + ms * 16 + r16) * 40 + quad * 8);
#pragma unroll
        for (int ns = 0; ns < 2; ++ns) {
            int n = ncol + ns * 16 + r16;
            bfr[ns] = *(const bf16x8*)(Bt + n * 40 + ((quad * 8) ^ (((n >> 3) & 3) * 8)));
        }
#pragma unroll
        for (int ms = 0; ms < 2; ++ms)
#pragma unroll
            for (int ns = 0; ns < 2; ++ns)
                acc[ms][ns] = __builtin_amdgcn_mfma_f32_16x16x32_bf16(
                    af[ms], bfr[ns], acc[ms][ns], 0, 0, 0);
        __syncthreads();
    }

#pragma unroll
    for (int ms = 0; ms < 2; ++ms)
#pragma unroll
        for (int ns = 0; ns < 2; ++ns) {
            int n = n0 + ncol + ns * 16 + r16;
            float bb = bias[n];
#pragma unroll
            for (int i = 0; i < 4; ++i) {
                int m = m0 + mrow + ms * 16 + quad * 4 + i;
                int bi = m >> 11, t = m & 2047;
                float v = acc[ms][ns][i] + bb;
                size_t idx = (t < 1024)
                    ? ((size_t)bi * 1024 + t) * 512 + n
                    : (size_t)2097152 + ((size_t)bi * 1024 + (t - 1024)) * 512 + n;
                out[idx] = v;
            }
        }
}

// ---------------------------------------------------------------------------
extern "C" void kernel_launch(void* const* d_in, const int* in_sizes, int n_in,
                              void* d_out, int out_size, void* d_ws, size_t ws_size,
                              hipStream_t stream)
{
    const float* self_seq  = (const float*)d_in[0];
    const float* cross_seq = (const float*)d_in[1];
    const int*   t_self    = (const int*)d_in[2];
    const int*   t_cross   = (const int*)d_in[3];
    const float* W_self    = (const float*)d_in[4];
    const float* b_self    = (const float*)d_in[5];
    const float* W_cross   = (const float*)d_in[6];
    const float* b_cross   = (const float*)d_in[7];
    const float* W_proj    = (const float*)d_in[8];
    const float* b_proj    = (const float*)d_in[9];
    float* out = (float*)d_out;

    // ws (32 MB): q, k, v, vt (4 x 4,194,304 bf16). ybuf aliases v (v dead
    // after vtrans). d_out slack (16.8 MB total) holds xb (8 MB) + wt (3 MB)
    // as scratch until proj overwrites everything.
    unsigned short* qbuf = (unsigned short*)d_ws;
    unsigned short* kbuf = qbuf + 4194304;
    unsigned short* vbuf = kbuf + 4194304;
    unsigned short* vtb  = vbuf + 4194304;
    unsigned short* ybuf = vbuf;                       // alias
    unsigned short* xb   = (unsigned short*)d_out;     // scratch in d_out
    unsigned short* wt   = xb + 4194304;

    prep_kernel<<<dim3(2432), 256, 0, stream>>>(
        self_seq, cross_seq, W_self, W_cross, xb, wt);

    qkv_kernel<<<dim3(32, 12, 2), 256, 0, stream>>>(
        xb, wt, b_self, b_cross, qbuf, kbuf, vbuf);

    vtrans_kernel<<<dim3(32, 32), 256, 0, stream>>>(vbuf, vtb);

    attn_kernel<<<dim3(32, 32), 128, 0, stream>>>(
        qbuf, kbuf, vtb, t_self, t_cross, ybuf);

    proj_kernel<<<dim3(128, 8), 256, 0, stream>>>(
        ybuf, W_proj, b_proj, out);
}

// Round 5
// 247.990 us; speedup vs baseline: 1.1364x; 1.1167x over previous
//
#include <hip/hip_runtime.h>

// ---------------------------------------------------------------------------
// SelfCrossAttention: B=4, T=1024+1024, d=512, H=8, hd=64. fp32 I/O,
// bf16 MFMA internals.
// prep (X->bf16, W->bf16 transposed, q pre-scaled 1/8)
//   -> qkv (128x128 tiles; V written transposed [bh][j][t])
//   -> attn (S^T flash: P exits QK^T directly in 16x16x16 B-operand layout,
//            no LDS roundtrip; fixed-max softmax exp(s) with O/l cancel;
//            4-way key split per block, LDS merge)
//   -> proj.
// ---------------------------------------------------------------------------

typedef short     bf16x8 __attribute__((ext_vector_type(8)));
typedef short     bf16x4 __attribute__((ext_vector_type(4)));
typedef float     f32x4  __attribute__((ext_vector_type(4)));
typedef int       i32x4  __attribute__((ext_vector_type(4)));

#define DI __device__ __forceinline__

DI unsigned short f2b(float f) {            // fp32 -> bf16 bits, RNE-ish
    union { float f; unsigned int u; } x; x.f = f;
    unsigned int r = x.u + 0x7fffu + ((x.u >> 16) & 1u);
    return (unsigned short)(r >> 16);
}
DI unsigned int fbits(float f) { union { float f; unsigned int u; } x; x.f = f; return x.u; }
DI float bitsf(unsigned int u) { union { unsigned int u; float f; } x; x.u = u; return x.f; }
DI float b2f(unsigned short v) { return bitsf(((unsigned int)v) << 16); }

// ---------------------------------------------------------------------------
// prep: [0,2048): X fp32 -> bf16 flat; [2048,2432): W -> wt[src][n][k] bf16,
// q-section (n<512) scaled by 0.125.
// ---------------------------------------------------------------------------
__global__ __launch_bounds__(256)
void prep_kernel(const float* __restrict__ Xs, const float* __restrict__ Xc,
                 const float* __restrict__ Ws, const float* __restrict__ Wc,
                 unsigned short* __restrict__ xb, unsigned short* __restrict__ wt)
{
    const int bid = blockIdx.x, tid = threadIdx.x;
    if (bid < 2048) {
        int idx = bid * 2048 + tid * 8;
        const float* s = (idx < 2097152) ? (Xs + idx) : (Xc + idx - 2097152);
        f32x4 a0 = *(const f32x4*)s;
        f32x4 a1 = *(const f32x4*)(s + 4);
        bf16x8 v;
#pragma unroll
        for (int j = 0; j < 4; ++j) {
            ((unsigned short*)&v)[j]     = f2b(a0[j]);
            ((unsigned short*)&v)[4 + j] = f2b(a1[j]);
        }
        *(bf16x8*)(xb + idx) = v;
        return;
    }
    __shared__ unsigned short Tt[64 * 72];
    int tj  = bid - 2048;
    int src = tj >= 192;  tj -= src * 192;
    int k0  = (tj / 24) * 64;
    int n0  = (tj % 24) * 64;
    const float* W = src ? Wc : Ws;
    float sc = (n0 < 512) ? 0.125f : 1.0f;
#pragma unroll
    for (int r = 0; r < 4; ++r) {
        int g  = tid + r * 256;
        int kr = g >> 4, nc4 = (g & 15) * 4;
        f32x4 v = *(const f32x4*)(W + (size_t)(k0 + kr) * 1536 + n0 + nc4);
#pragma unroll
        for (int u = 0; u < 4; ++u)
            Tt[(nc4 + u) * 72 + kr] = f2b(v[u] * sc);
    }
    __syncthreads();
#pragma unroll
    for (int r = 0; r < 2; ++r) {
        int c = tid + r * 256;
        int nl = c >> 3, k8 = (c & 7) * 8;
        *(bf16x8*)(wt + (size_t)src * 786432 + (size_t)(n0 + nl) * 512 + k0 + k8) =
            *(const bf16x8*)(Tt + nl * 72 + k8);
    }
}

// ---------------------------------------------------------------------------
// QKV: xb @ wt^T + bias. 128x128 tile, 256 thr. q/k -> [bh][t][j];
// v -> vt[bh][j][t] directly (packed b64 stores, vtrans eliminated).
// ---------------------------------------------------------------------------
__global__ __launch_bounds__(256)
void qkv_kernel(const unsigned short* __restrict__ xb,
                const unsigned short* __restrict__ wt,
                const float* __restrict__ bs, const float* __restrict__ bc,
                unsigned short* __restrict__ qb, unsigned short* __restrict__ kb,
                unsigned short* __restrict__ vtb)
{
    const int src = blockIdx.z;
    const int m0 = blockIdx.x * 128, n0 = blockIdx.y * 128;
    const float* bias = src ? bc : bs;
    const unsigned short* X = xb + (size_t)src * 2097152;
    const unsigned short* W = wt + (size_t)src * 786432;

    __shared__ unsigned short As[128 * 40];
    __shared__ unsigned short Bs[128 * 40];

    const int tid = threadIdx.x, lane = tid & 63, w = tid >> 6;
    const int quad = lane >> 4, r16 = lane & 15;
    const int mrow = (w >> 1) * 64, ncol = (w & 1) * 64;

    const f32x4 fz = {0.f, 0.f, 0.f, 0.f};
    f32x4 acc[4][4];
#pragma unroll
    for (int a = 0; a < 4; ++a)
#pragma unroll
        for (int b = 0; b < 4; ++b) acc[a][b] = fz;

    const int srow = tid >> 2, sk8 = (tid & 3) * 8;

    for (int k0 = 0; k0 < 512; k0 += 32) {
#pragma unroll
        for (int r = 0; r < 2; ++r) {
            int row = srow + r * 64;
            bf16x8 av = *(const bf16x8*)(X + (size_t)(m0 + row) * 512 + k0 + sk8);
            bf16x8 bv = *(const bf16x8*)(W + (size_t)(n0 + row) * 512 + k0 + sk8);
            *(bf16x8*)(As + row * 40 + sk8) = av;
            *(bf16x8*)(Bs + row * 40 + (sk8 ^ (((row >> 3) & 3) * 8))) = bv;
        }
        __syncthreads();

        bf16x8 af[4], bfr[4];
#pragma unroll
        for (int ms = 0; ms < 4; ++ms)
            af[ms] = *(const bf16x8*)(As + (mrow + ms * 16 + r16) * 40 + quad * 8);
#pragma unroll
        for (int ns = 0; ns < 4; ++ns) {
            int n = ncol + ns * 16 + r16;
            bfr[ns] = *(const bf16x8*)(Bs + n * 40 + ((quad * 8) ^ (((n >> 3) & 3) * 8)));
        }
#pragma unroll
        for (int ms = 0; ms < 4; ++ms)
#pragma unroll
            for (int ns = 0; ns < 4; ++ns)
                acc[ms][ns] = __builtin_amdgcn_mfma_f32_16x16x32_bf16(
                    af[ms], bfr[ns], acc[ms][ns], 0, 0, 0);
        __syncthreads();
    }

#pragma unroll
    for (int ms = 0; ms < 4; ++ms)
#pragma unroll
        for (int ns = 0; ns < 4; ++ns) {
            int n = n0 + ncol + ns * 16 + r16;
            int sec = n >> 9, col = n & 511;
            int hh = col >> 6, j = col & 63;
            float bb = bias[n] * ((sec == 0) ? 0.125f : 1.0f);
            int mb = m0 + mrow + ms * 16 + quad * 4;
            int bi = mb >> 10, tg0 = (mb & 1023) + (src << 10);
            if (sec == 2) {                 // V: transposed packed store
                bf16x4 pk;
#pragma unroll
                for (int i = 0; i < 4; ++i)
                    pk[i] = (short)f2b(acc[ms][ns][i] + bb);
                *(bf16x4*)(vtb + (((size_t)(bi * 8 + hh) * 64 + j) << 11) + tg0) = pk;
            } else {
                unsigned short* dst = (sec == 0) ? qb : kb;
#pragma unroll
                for (int i = 0; i < 4; ++i)
                    dst[(((size_t)(bi * 8 + hh) * 2048 + tg0 + i) << 6) + j] =
                        f2b(acc[ms][ns][i] + bb);
            }
        }
}

// ---------------------------------------------------------------------------
// attn: S^T flash. Block 256 thr = 4 waves; block = 64 queries of one bh;
// wave = all 64 q x 8 K-tiles (4-way key split). S^T = K·Q^T (C-layout
// row=key, col=query) -> exp -> truncate-pack == 16x16x16 B-operand, fed
// straight to O^T = V^T·P^T. Partial O^T/l merged via LDS (fixed-max:
// merge = plain sum). Grid swizzled so XCD sees 4 bh (L2-resident K/V).
// ---------------------------------------------------------------------------
__global__ __launch_bounds__(256)
void attn_kernel(const unsigned short* __restrict__ qb,
                 const unsigned short* __restrict__ kb,
                 const unsigned short* __restrict__ vt,
                 const int* __restrict__ t_self, const int* __restrict__ t_cross,
                 unsigned short* __restrict__ y)
{
    const int bid = blockIdx.x;
    const int bh = ((bid & 7) << 2) | ((bid >> 3) & 3);   // XCD-local bh group
    const int qt = bid >> 5;
    const int b = bh >> 3, h = bh & 7;
    const int tid = threadIdx.x, ksplit = tid >> 6, lane = tid & 63;
    const int quad = lane >> 4, r16 = lane & 15;

    const unsigned short* Q = qb + (size_t)bh * 131072;
    const unsigned short* K = kb + (size_t)bh * 131072;
    const unsigned short* V = vt + (size_t)bh * 131072;
    const int* tsb = t_self + b * 1024;
    const int* tcb = t_cross + b * 1024;

    __shared__ unsigned short Op[4][64 * 68];   // bf16 partial O^T per split
    __shared__ float Ls[4][64];

    const int q0 = qt * 64;

    bf16x8 qf[4][2];
#pragma unroll
    for (int g = 0; g < 4; ++g)
#pragma unroll
        for (int ks = 0; ks < 2; ++ks)
            qf[g][ks] = *(const bf16x8*)(Q + (size_t)(q0 + g * 16 + r16) * 64
                                           + ks * 32 + quad * 8);

    const int* tqp = (qt < 16) ? (tsb + qt * 64) : (tcb + (qt - 16) * 64);
    int tq[4];
#pragma unroll
    for (int g = 0; g < 4; ++g) tq[g] = tqp[g * 16 + r16];

    const f32x4 fz = {0.f, 0.f, 0.f, 0.f};
    f32x4 ot[4][4];
    float rs[4] = {0.f, 0.f, 0.f, 0.f};
#pragma unroll
    for (int g = 0; g < 4; ++g)
#pragma unroll
        for (int nt = 0; nt < 4; ++nt) ot[g][nt] = fz;

    for (int it = 0; it < 8; ++it) {
        const int kt = ksplit * 8 + it;
        const int krow = kt * 64;
        const int* tkp = (kt < 16) ? (tsb + krow) : (tcb + krow - 1024);

#pragma unroll
        for (int ct = 0; ct < 4; ++ct) {
            i32x4 tk = *(const i32x4*)(tkp + ct * 16 + quad * 4);
            bf16x8 ka0 = *(const bf16x8*)(K + (size_t)(krow + ct * 16 + r16) * 64 + quad * 8);
            bf16x8 ka1 = *(const bf16x8*)(K + (size_t)(krow + ct * 16 + r16) * 64 + 32 + quad * 8);

            // S^T for all 4 query groups, exp, pack into B-operand regs
            unsigned int pf[4][2];
#pragma unroll
            for (int g = 0; g < 4; ++g) {
                f32x4 st = fz;
                st = __builtin_amdgcn_mfma_f32_16x16x32_bf16(ka0, qf[g][0], st, 0, 0, 0);
                st = __builtin_amdgcn_mfma_f32_16x16x32_bf16(ka1, qf[g][1], st, 0, 0, 0);
                unsigned int u[4];
#pragma unroll
                for (int i = 0; i < 4; ++i) {
                    float a = (tq[g] >= tk[i]) ? st[i] : -1e9f;  // select ARG, no inf
                    a = fminf(a, 80.f);
                    u[i] = fbits(__expf(a)) & 0xFFFF0000u;       // truncate to bf16
                    rs[g] += bitsf(u[i]);                        // l == sum of stored P
                }
                pf[g][0] = (u[0] >> 16) | u[1];
                pf[g][1] = (u[2] >> 16) | u[3];
            }

            // O^T += V^T · P^T  (V^T A-frags direct b64 from global)
#pragma unroll
            for (int nt = 0; nt < 4; ++nt) {
                bf16x4 va = *(const bf16x4*)(V + (size_t)(nt * 16 + r16) * 2048
                                               + krow + ct * 16 + quad * 4);
#pragma unroll
                for (int g = 0; g < 4; ++g) {
                    union { unsigned int u[2]; bf16x4 v; } pu;
                    pu.u[0] = pf[g][0]; pu.u[1] = pf[g][1];
                    ot[g][nt] = __builtin_amdgcn_mfma_f32_16x16x16bf16_1k(
                        va, pu.v, ot[g][nt], 0, 0, 0);
                }
            }
        }
    }

    // partial-l: sum across the 4 quads (keys) for each query column
#pragma unroll
    for (int g = 0; g < 4; ++g) {
        rs[g] += __shfl_xor(rs[g], 16);
        rs[g] += __shfl_xor(rs[g], 32);
    }

    // write partials (bf16 O^T, fp32 l) and merge
    unsigned short* opw = Op[ksplit];
#pragma unroll
    for (int g = 0; g < 4; ++g)
#pragma unroll
        for (int nt = 0; nt < 4; ++nt) {
            union { unsigned int u[2]; bf16x4 v; } pk;
            pk.u[0] = (unsigned int)f2b(ot[g][nt][0]) | ((unsigned int)f2b(ot[g][nt][1]) << 16);
            pk.u[1] = (unsigned int)f2b(ot[g][nt][2]) | ((unsigned int)f2b(ot[g][nt][3]) << 16);
            *(bf16x4*)(opw + (g * 16 + r16) * 68 + nt * 16 + quad * 4) = pk.v;
        }
    if (quad == 0) {
#pragma unroll
        for (int g = 0; g < 4; ++g) Ls[ksplit][g * 16 + r16] = rs[g];
    }
    __syncthreads();

    for (int c = tid; c < 1024; c += 256) {
        int q = c >> 4, j4 = (c & 15) * 4;
        float l = Ls[0][q] + Ls[1][q] + Ls[2][q] + Ls[3][q];
        float inv = (l > 0.f) ? (1.f / l) : 0.f;
        float s[4] = {0.f, 0.f, 0.f, 0.f};
#pragma unroll
        for (int sp = 0; sp < 4; ++sp) {
            bf16x4 v = *(const bf16x4*)(Op[sp] + q * 68 + j4);
#pragma unroll
            for (int i = 0; i < 4; ++i)
                s[i] += b2f(((const unsigned short*)&v)[i]);
        }
        bf16x4 pk;
#pragma unroll
        for (int i = 0; i < 4; ++i) pk[i] = (short)f2b(s[i] * inv);
        *(bf16x4*)(y + (((size_t)(b * 2048 + q0 + q)) << 9) + h * 64 + j4) = pk;
    }
}

// ---------------------------------------------------------------------------
// proj: Y(8192x512 bf16) @ W_proj(512x512 fp32) + b -> fp32 out (tuple split)
// ---------------------------------------------------------------------------
__global__ __launch_bounds__(256)
void proj_kernel(const unsigned short* __restrict__ X,
                 const float* __restrict__ W, const float* __restrict__ bias,
                 float* __restrict__ out)
{
    const int m0 = blockIdx.x * 64, n0 = blockIdx.y * 64;
    __shared__ unsigned short As[64 * 40];
    __shared__ unsigned short Bt[64 * 40];

    const int tid = threadIdx.x, lane = tid & 63, w = tid >> 6;
    const int quad = lane >> 4, r16 = lane & 15;
    const int mrow = (w >> 1) * 32, ncol = (w & 1) * 32;

    const f32x4 fz = {0.f, 0.f, 0.f, 0.f};
    f32x4 acc[2][2];
    acc[0][0] = fz; acc[0][1] = fz; acc[1][0] = fz; acc[1][1] = fz;

    const int a_row = tid >> 2, a_k = (tid & 3) * 8;
    const int b_k = tid >> 3, b_n8 = (tid & 7) * 8;

    for (int k0 = 0; k0 < 512; k0 += 32) {
        bf16x8 av = *(const bf16x8*)(X + (size_t)(m0 + a_row) * 512 + k0 + a_k);
        const float* bp = W + (size_t)(k0 + b_k) * 512 + n0 + b_n8;
        f32x4 b0 = *(const f32x4*)bp;
        f32x4 b1 = *(const f32x4*)(bp + 4);
        *(bf16x8*)(As + a_row * 40 + a_k) = av;
#pragma unroll
        for (int jj = 0; jj < 8; ++jj) {
            int n = b_n8 + jj;
            int c = ((n >> 3) & 3) * 8;
            Bt[n * 40 + (b_k ^ c)] = f2b((jj < 4) ? b0[jj & 3] : b1[jj & 3]);
        }
        __syncthreads();

        bf16x8 af[2], bfr[2];
#pragma unroll
        for (int ms = 0; ms < 2; ++ms)
            af[ms] = *(const bf16x8*)(As + (mrow + ms * 16 + r16) * 40 + quad * 8);
#pragma unroll
        for (int ns = 0; ns < 2; ++ns) {
            int n = ncol + ns * 16 + r16;
            bfr[ns] = *(const bf16x8*)(Bt + n * 40 + ((quad * 8) ^ (((n >> 3) & 3) * 8)));
        }
#pragma unroll
        for (int ms = 0; ms < 2; ++ms)
#pragma unroll
            for (int ns = 0; ns < 2; ++ns)
                acc[ms][ns] = __builtin_amdgcn_mfma_f32_16x16x32_bf16(
                    af[ms], bfr[ns], acc[ms][ns], 0, 0, 0);
        __syncthreads();
    }

#pragma unroll
    for (int ms = 0; ms < 2; ++ms)
#pragma unroll
        for (int ns = 0; ns < 2; ++ns) {
            int n = n0 + ncol + ns * 16 + r16;
            float bb = bias[n];
#pragma unroll
            for (int i = 0; i < 4; ++i) {
                int m = m0 + mrow + ms * 16 + quad * 4 + i;
                int bi = m >> 11, t = m & 2047;
                float v = acc[ms][ns][i] + bb;
                size_t idx = (t < 1024)
                    ? ((size_t)bi * 1024 + t) * 512 + n
                    : (size_t)2097152 + ((size_t)bi * 1024 + (t - 1024)) * 512 + n;
                out[idx] = v;
            }
        }
}

// ---------------------------------------------------------------------------
extern "C" void kernel_launch(void* const* d_in, const int* in_sizes, int n_in,
                              void* d_out, int out_size, void* d_ws, size_t ws_size,
                              hipStream_t stream)
{
    const float* self_seq  = (const float*)d_in[0];
    const float* cross_seq = (const float*)d_in[1];
    const int*   t_self    = (const int*)d_in[2];
    const int*   t_cross   = (const int*)d_in[3];
    const float* W_self    = (const float*)d_in[4];
    const float* b_self    = (const float*)d_in[5];
    const float* W_cross   = (const float*)d_in[6];
    const float* b_cross   = (const float*)d_in[7];
    const float* W_proj    = (const float*)d_in[8];
    const float* b_proj    = (const float*)d_in[9];
    float* out = (float*)d_out;

    // ws (32 MB): q, k, vt, y (4 x 4,194,304 bf16). d_out slack holds xb/wt.
    unsigned short* qbuf = (unsigned short*)d_ws;
    unsigned short* kbuf = qbuf + 4194304;
    unsigned short* vtb  = kbuf + 4194304;
    unsigned short* ybuf = vtb + 4194304;
    unsigned short* xb   = (unsigned short*)d_out;   // scratch until proj
    unsigned short* wt   = xb + 4194304;

    prep_kernel<<<dim3(2432), 256, 0, stream>>>(
        self_seq, cross_seq, W_self, W_cross, xb, wt);

    qkv_kernel<<<dim3(32, 12, 2), 256, 0, stream>>>(
        xb, wt, b_self, b_cross, qbuf, kbuf, vtb);

    attn_kernel<<<dim3(1024), 256, 0, stream>>>(
        qbuf, kbuf, vtb, t_self, t_cross, ybuf);

    proj_kernel<<<dim3(128, 8), 256, 0, stream>>>(
        ybuf, W_proj, b_proj, out);
}